// Round 3
// baseline (22.775 us; speedup 1.0000x reference)
//
#include <hip/hip_runtime.h>

// CollisionLoss: loss = sum_{b,t,n} relu(tx[b,n] - |ex[b,t]-cx[b,n]|)
//                              * relu(ty[b,n] - |ey[b,t]-cy[b,n]|) * valid
//                / max(sum(ego_mask>=1), 1)
// pred_abs (B,T,2) f32, gt_bboxes (B,N,9) f32, ego_masks (B,T) i32,
// agent_mask (B,N) i32. B=4096, T=12, N=512.
//
// R1: same-address atomics serialized everything (153us). R2: 21.5us with
// 10 scalar uncoalesced loads/thread. R3: coalesced float4 LDS staging of
// the 36B-stride bbox slab + float2-packed partials for a single-stream
// reduce.

#define T_DIM 12
#define N_DIM 512
#define SLAB4 1152   // N*9*4B / 16B = 1152 float4 per batch

__global__ __launch_bounds__(256) void collision_loss_main(
    const float* __restrict__ pred_abs,   // (B,T,2)
    const float* __restrict__ gt_bboxes,  // (B,N,9)
    const int*   __restrict__ ego_masks,  // (B,T)
    const int*   __restrict__ agent_mask, // (B,N)
    float2* __restrict__ ws)              // (B) {partial loss, ego count}
{
    __shared__ float4 s_slab4[SLAB4];     // 18432 B raw bbox slab
    __shared__ float  s_ex[T_DIM];
    __shared__ float  s_ey[T_DIM];
    __shared__ float  s_part[4];

    const int b   = blockIdx.x;   // one block per batch element
    const int tid = threadIdx.x;

    // ---- Coalesced stage: whole (512,9) f32 slab as sequential float4 ----
    const float4* __restrict__ src4 =
        (const float4*)(gt_bboxes + (size_t)b * (N_DIM * 9));
    #pragma unroll
    for (int i = 0; i < 4; ++i)
        s_slab4[tid + i * 256] = src4[tid + i * 256];
    if (tid < SLAB4 - 1024)
        s_slab4[tid + 1024] = src4[tid + 1024];

    // ---- Ego trajectory; invalid ego -> ex=+1e30 => relu term = 0 ----
    int ev = 0;
    if (tid < T_DIM) {
        ev = (ego_masks[b * T_DIM + tid] >= 1) ? 1 : 0;
        const float ex = pred_abs[(b * T_DIM + tid) * 2 + 0];
        const float ey = pred_abs[(b * T_DIM + tid) * 2 + 1];
        s_ex[tid] = ev ? ex : 1e30f;
        s_ey[tid] = ev ? ey : 1e30f;
    }
    const unsigned long long bm = __ballot(ev != 0); // wave0 lanes 0..11
    const int cnt = __popcll(bm);                    // valid at tid==0

    // Coalesced mask loads (thread owns agents tid and tid+256).
    const int av0 = agent_mask[b * N_DIM + tid] >= 1;
    const int av1 = agent_mask[b * N_DIM + tid + 256] >= 1;

    __syncthreads();

    // ---- Per-agent fields from LDS (stride-9 dwords: conflict-free) ----
    const float* __restrict__ s_bbox = (const float*)s_slab4;
    const int o0 = tid * 9, o1 = (tid + 256) * 9;
    const float cx0 = s_bbox[o0 + 0], cy0 = s_bbox[o0 + 1];
    const float ax0 = s_bbox[o0 + 3], ay0 = s_bbox[o0 + 4];
    const float cx1 = s_bbox[o1 + 0], cy1 = s_bbox[o1 + 1];
    const float ax1 = s_bbox[o1 + 3], ay1 = s_bbox[o1 + 4];

    // Invalid agent -> tx = -1e30 => relu term = 0 (branch-free loop).
    const float tx0 = av0 ? ((1.85f + 0.5f) * 0.5f + ax0 * 0.5f + 1.5f) : -1e30f;
    const float tx1 = av1 ? ((1.85f + 0.5f) * 0.5f + ax1 * 0.5f + 1.5f) : -1e30f;
    const float ty0 = (4.084f + 0.5f) * 0.5f + ay0 * 0.5f + 1.5f;
    const float ty1 = (4.084f + 0.5f) * 0.5f + ay1 * 0.5f + 1.5f;

    float acc = 0.0f;
    #pragma unroll
    for (int t = 0; t < T_DIM; ++t) {
        const float ex = s_ex[t], ey = s_ey[t];   // broadcast reads
        const float px0 = fmaxf(tx0 - fabsf(ex - cx0), 0.0f);
        const float py0 = fmaxf(ty0 - fabsf(ey - cy0), 0.0f);
        const float px1 = fmaxf(tx1 - fabsf(ex - cx1), 0.0f);
        const float py1 = fmaxf(ty1 - fabsf(ey - cy1), 0.0f);
        acc += px0 * py0 + px1 * py1;
    }

    // ---- Block reduction: wave shuffle then LDS across 4 waves ----
    #pragma unroll
    for (int off = 32; off > 0; off >>= 1) acc += __shfl_down(acc, off);
    const int wave = tid >> 6;
    if ((tid & 63) == 0) s_part[wave] = acc;
    __syncthreads();
    if (tid == 0) {
        const float L = s_part[0] + s_part[1] + s_part[2] + s_part[3];
        ws[b] = make_float2(L, (float)cnt);
    }
}

// Single-block reduce of B float2 partials -> out[0].
__global__ __launch_bounds__(1024) void collision_loss_reduce(
    const float2* __restrict__ ws, float* __restrict__ out, int nB)
{
    __shared__ float s_l[16];
    __shared__ float s_c[16];
    const int tid = threadIdx.x;

    float l = 0.0f, c = 0.0f;
    for (int i = tid; i < nB; i += 1024) {
        const float2 v = ws[i];
        l += v.x;
        c += v.y;
    }
    #pragma unroll
    for (int off = 32; off > 0; off >>= 1) {
        l += __shfl_down(l, off);
        c += __shfl_down(c, off);
    }
    const int wave = tid >> 6;
    if ((tid & 63) == 0) { s_l[wave] = l; s_c[wave] = c; }
    __syncthreads();
    if (tid == 0) {
        float L = 0.0f, C = 0.0f;
        #pragma unroll
        for (int w = 0; w < 16; ++w) { L += s_l[w]; C += s_c[w]; }
        out[0] = L / fmaxf(C, 1.0f);
    }
}

extern "C" void kernel_launch(void* const* d_in, const int* in_sizes, int n_in,
                              void* d_out, int out_size, void* d_ws, size_t ws_size,
                              hipStream_t stream)
{
    const float* pred_abs   = (const float*)d_in[0];
    const float* gt_bboxes  = (const float*)d_in[1];
    const int*   ego_masks  = (const int*)d_in[2];
    const int*   agent_mask = (const int*)d_in[3];
    float* out = (float*)d_out;

    const int B = in_sizes[0] / (T_DIM * 2);  // 4096

    float2* ws = (float2*)d_ws;

    collision_loss_main<<<dim3(B), 256, 0, stream>>>(
        pred_abs, gt_bboxes, ego_masks, agent_mask, ws);

    collision_loss_reduce<<<dim3(1), 1024, 0, stream>>>(ws, out, B);
}

// Round 4
// 21.022 us; speedup vs baseline: 1.0834x; 1.0834x over previous
//
#include <hip/hip_runtime.h>

// CollisionLoss: loss = sum_{b,t,n} relu(tx[b,n] - |ex[b,t]-cx[b,n]|)
//                              * relu(ty[b,n] - |ey[b,t]-cy[b,n]|) * valid
//                / max(sum(ego_mask>=1), 1)
// pred_abs (B,T,2) f32, gt_bboxes (B,N,9) f32, ego_masks (B,T) i32,
// agent_mask (B,N) i32. B=4096, T=12, N=512.
//
// R1: same-address atomics serialized (153us). R2: 21.5us, scalar loads.
// R3: coalesced LDS staging neutral (22.8us) -> not coalescing-bound.
// R4: discriminate latency-bound vs L3-line-movement-bound: 2 batches/block,
//     4 agents/thread, dwordx4+dword loads all issued upfront (2x MLP payload
//     per thread, half the waves per unit work).

#define T_DIM 12
#define N_DIM 512

__global__ __launch_bounds__(256) void collision_loss_main(
    const float* __restrict__ pred_abs,   // (B,T,2)
    const float* __restrict__ gt_bboxes,  // (B,N,9)
    const int*   __restrict__ ego_masks,  // (B,T)
    const int*   __restrict__ agent_mask, // (B,N)
    float2* __restrict__ ws)              // (grid) {partial loss, ego count}
{
    __shared__ float s_ex[2][T_DIM];
    __shared__ float s_ey[2][T_DIM];
    __shared__ float s_part[4];

    const int b0  = blockIdx.x * 2;       // this block owns batches b0, b0+1
    const int tid = threadIdx.x;

    // ---- Ego staging for both batches; invalid ego -> +1e30 => term 0 ----
    int ev = 0;
    if (tid < 2 * T_DIM) {                // 24 lanes of wave 0
        const int bb = tid / T_DIM;
        const int t  = tid % T_DIM;
        const int b  = b0 + bb;
        ev = (ego_masks[b * T_DIM + t] >= 1) ? 1 : 0;
        const float ex = pred_abs[(b * T_DIM + t) * 2 + 0];
        const float ey = pred_abs[(b * T_DIM + t) * 2 + 1];
        s_ex[bb][t] = ev ? ex : 1e30f;
        s_ey[bb][t] = ev ? ey : 1e30f;
    }
    const unsigned long long bm = __ballot(ev != 0);
    const int cnt = __popcll(bm);         // total valid ego steps, both batches

    // ---- All agent loads issued upfront: 4 agents x (dwordx4 + dword) ----
    // Agent a: (batch b0 + a/2, n = tid + (a&1)*256).
    const float* base = gt_bboxes + (size_t)b0 * (N_DIM * 9);
    const float4 f0 = *(const float4*)(base + (size_t)(tid      ) * 9);
    const float  g0 = *(base + (size_t)(tid      ) * 9 + 4);
    const float4 f1 = *(const float4*)(base + (size_t)(tid + 256) * 9);
    const float  g1 = *(base + (size_t)(tid + 256) * 9 + 4);
    const float4 f2 = *(const float4*)(base + (size_t)(tid + 512) * 9);
    const float  g2 = *(base + (size_t)(tid + 512) * 9 + 4);
    const float4 f3 = *(const float4*)(base + (size_t)(tid + 768) * 9);
    const float  g3 = *(base + (size_t)(tid + 768) * 9 + 4);

    const int* am = agent_mask + b0 * N_DIM;
    const int av0 = am[tid]       >= 1;
    const int av1 = am[tid + 256] >= 1;
    const int av2 = am[tid + 512] >= 1;
    const int av3 = am[tid + 768] >= 1;

    // Invalid agent -> tx = -1e30 => relu term 0 (branch-free loop).
    const float tx0 = av0 ? (1.175f + f0.w * 0.5f + 1.5f) : -1e30f;
    const float tx1 = av1 ? (1.175f + f1.w * 0.5f + 1.5f) : -1e30f;
    const float tx2 = av2 ? (1.175f + f2.w * 0.5f + 1.5f) : -1e30f;
    const float tx3 = av3 ? (1.175f + f3.w * 0.5f + 1.5f) : -1e30f;
    const float ty0 = 2.292f + g0 * 0.5f + 1.5f;
    const float ty1 = 2.292f + g1 * 0.5f + 1.5f;
    const float ty2 = 2.292f + g2 * 0.5f + 1.5f;
    const float ty3 = 2.292f + g3 * 0.5f + 1.5f;

    __syncthreads();

    float acc = 0.0f;
    #pragma unroll
    for (int t = 0; t < T_DIM; ++t) {
        const float exA = s_ex[0][t], eyA = s_ey[0][t];
        const float exB = s_ex[1][t], eyB = s_ey[1][t];
        const float px0 = fmaxf(tx0 - fabsf(exA - f0.x), 0.0f);
        const float py0 = fmaxf(ty0 - fabsf(eyA - f0.y), 0.0f);
        const float px1 = fmaxf(tx1 - fabsf(exA - f1.x), 0.0f);
        const float py1 = fmaxf(ty1 - fabsf(eyA - f1.y), 0.0f);
        const float px2 = fmaxf(tx2 - fabsf(exB - f2.x), 0.0f);
        const float py2 = fmaxf(ty2 - fabsf(eyB - f2.y), 0.0f);
        const float px3 = fmaxf(tx3 - fabsf(exB - f3.x), 0.0f);
        const float py3 = fmaxf(ty3 - fabsf(eyB - f3.y), 0.0f);
        acc += px0 * py0 + px1 * py1 + px2 * py2 + px3 * py3;
    }

    // ---- Block reduction: wave shuffle then LDS across 4 waves ----
    #pragma unroll
    for (int off = 32; off > 0; off >>= 1) acc += __shfl_down(acc, off);
    const int wave = tid >> 6;
    if ((tid & 63) == 0) s_part[wave] = acc;
    __syncthreads();
    if (tid == 0) {
        const float L = s_part[0] + s_part[1] + s_part[2] + s_part[3];
        ws[blockIdx.x] = make_float2(L, (float)cnt);
    }
}

// Single-block reduce of nP float2 partials -> out[0].
__global__ __launch_bounds__(1024) void collision_loss_reduce(
    const float2* __restrict__ ws, float* __restrict__ out, int nP)
{
    __shared__ float s_l[16];
    __shared__ float s_c[16];
    const int tid = threadIdx.x;

    float l = 0.0f, c = 0.0f;
    for (int i = tid; i < nP; i += 1024) {
        const float2 v = ws[i];
        l += v.x;
        c += v.y;
    }
    #pragma unroll
    for (int off = 32; off > 0; off >>= 1) {
        l += __shfl_down(l, off);
        c += __shfl_down(c, off);
    }
    const int wave = tid >> 6;
    if ((tid & 63) == 0) { s_l[wave] = l; s_c[wave] = c; }
    __syncthreads();
    if (tid == 0) {
        float L = 0.0f, C = 0.0f;
        #pragma unroll
        for (int w = 0; w < 16; ++w) { L += s_l[w]; C += s_c[w]; }
        out[0] = L / fmaxf(C, 1.0f);
    }
}

extern "C" void kernel_launch(void* const* d_in, const int* in_sizes, int n_in,
                              void* d_out, int out_size, void* d_ws, size_t ws_size,
                              hipStream_t stream)
{
    const float* pred_abs   = (const float*)d_in[0];
    const float* gt_bboxes  = (const float*)d_in[1];
    const int*   ego_masks  = (const int*)d_in[2];
    const int*   agent_mask = (const int*)d_in[3];
    float* out = (float*)d_out;

    const int B = in_sizes[0] / (T_DIM * 2);  // 4096
    const int grid = B / 2;                   // 2048 blocks, 2 batches each

    float2* ws = (float2*)d_ws;

    collision_loss_main<<<dim3(grid), 256, 0, stream>>>(
        pred_abs, gt_bboxes, ego_masks, agent_mask, ws);

    collision_loss_reduce<<<dim3(1), 1024, 0, stream>>>(ws, out, grid);
}